// Round 4
// baseline (192.647 us; speedup 1.0000x reference)
//
#include <hip/hip_runtime.h>
#include <stdint.h>

// Head: x[8,2048,1024] fp32; Wk/Wq/Wv [1024,64] fp32 -> out [8,2048,64] fp32
// R12 (resubmit — R3 bench was an acquisition timeout, no data).
// qkv = wave-private global_load_lds staging, ZERO barriers.
// R10/R11 proved register-resident prefetch gets serialized by regalloc
// (VGPR_Count 32/88 < required; ~600cyc/load dependent chain). R4 proved
// LDS staging works but its block-wide syncthreads+vmcnt(0) drains convoy
// 8 waves -> 40.8us. Here each wave stages ITS OWN frags into private LDS
// (global src per-lane chosen so each lane stages exactly its own MFMA
// fragment -> ds_read is base+lane*16, conflict-free, no swizzle). No
// __syncthreads: wave-local asm vmcnt(0) is exact (only this wave's 10
// stages outstanding). 1024 blocks x 16-row tiles, 80KB LDS, 2 blocks/CU.
// wconv + attn unchanged (R9 best).

#define B_ 8
#define T_ 2048
#define C_ 1024
#define H_ 64

typedef float f32x4 __attribute__((ext_vector_type(4)));
typedef short s16x8 __attribute__((ext_vector_type(8)));

__device__ __forceinline__ unsigned int rhu16(float f) {
    return (__float_as_uint(f) + 0x8000u) >> 16;
}
__device__ __forceinline__ unsigned int pkbf(float lo, float hi) {
    unsigned int a = __float_as_uint(lo) + 0x8000u;
    unsigned int b = __float_as_uint(hi) + 0x8000u;
    return __builtin_amdgcn_perm(b, a, 0x07060302u);   // bytes [b3 b2 a3 a2]
}
// async global->LDS, 16B per lane; LDS dest = wave-uniform base + lane*16
__device__ __forceinline__ void ld_lds16(const void* g, void* l) {
    __builtin_amdgcn_global_load_lds(
        (const __attribute__((address_space(1))) unsigned int*)g,
        (__attribute__((address_space(3))) unsigned int*)l, 16, 0, 0);
}

// ---------------------------------------------------------------------------
// K0: 48 blocks = 3 mats x 16 c-groups of 64. Coalesced read, LDS transpose
// (stride 65), coalesced bf16 write. Wq pre-scaled by 1/32 (C^-0.5).
// ---------------------------------------------------------------------------
__global__ __launch_bounds__(256) void wconv(const float* __restrict__ Wk,
        const float* __restrict__ Wq, const float* __restrict__ Wv,
        unsigned short* __restrict__ Wt) {
    __shared__ float ls[64 * 65];
    const int bx = blockIdx.x, t = threadIdx.x;
    const int mat = bx >> 4, c0 = (bx & 15) << 6;
    const float* W = (mat == 0) ? Wk : ((mat == 1) ? Wq : Wv);
    const float sc = (mat == 1) ? 0.03125f : 1.0f;
    #pragma unroll
    for (int k = 0; k < 4; k++) {
        int i = t + (k << 8);
        int cr = i >> 4, hq = (i & 15) << 2;
        float4 v = *reinterpret_cast<const float4*>(&W[(size_t)(c0 + cr) * H_ + hq]);
        ls[cr * 65 + hq + 0] = v.x; ls[cr * 65 + hq + 1] = v.y;
        ls[cr * 65 + hq + 2] = v.z; ls[cr * 65 + hq + 3] = v.w;
    }
    __syncthreads();
    #pragma unroll
    for (int k = 0; k < 4; k++) {
        int i = t + (k << 8);
        int h = i >> 4, cq = (i & 15) << 2;
        float a = ls[(cq + 0) * 65 + h] * sc, b = ls[(cq + 1) * 65 + h] * sc;
        float c = ls[(cq + 2) * 65 + h] * sc, d = ls[(cq + 3) * 65 + h] * sc;
        uint2 o; o.x = pkbf(a, b); o.y = pkbf(c, d);
        *reinterpret_cast<uint2*>(&Wt[(size_t)(mat * 64 + h) * C_ + c0 + cq]) = o;
    }
}

// ---------------------------------------------------------------------------
// K1: QKV projection — wave-private async LDS staging, no barriers.
// 1024 blocks x 256 thr; block = 16 rows x 192 cols, wave = 16 rows x 48
// cols. Per 64-k chunk per wave: 10 global_load_lds (4 x-frags, 6 W-frags;
// each lane's 16B IS its own MFMA fragment piece), 10 ds_read_b128, 8 pkbf,
// 6 MFMA. Double-buffered 20KB/wave; wave-local vmcnt(0) at chunk top is
// exact (only own stages outstanding). Overlap = one full compute phase.
// ---------------------------------------------------------------------------
__global__ __launch_bounds__(256) __attribute__((amdgpu_waves_per_eu(2, 2)))
void qkv(const float* __restrict__ x,
        const unsigned short* __restrict__ Wt,
        unsigned short* __restrict__ kb, unsigned short* __restrict__ qb,
        unsigned short* __restrict__ vtb) {
    __shared__ __align__(16) char smem[81920];   // 4 waves x 2 buf x 10KB
    const int t = threadIdx.x, lane = t & 63, w = t >> 6;
    const int l15 = lane & 15, quad = lane >> 4;
    const int bx = blockIdx.x;
    const int bb = bx >> 7;                 // batch
    const int mt = bx & 127;                // 16-row tile within batch
    const int m0 = bb * T_ + mt * 16;
    const int colb = w * 48;

    // stage source bases: lane l stages row (l&15), k-slot quad*8(+h*4)
    const float* xgb = x + (size_t)(m0 + l15) * C_ + quad * 8;
    const unsigned short* wgb = Wt + (size_t)(colb + l15) * C_ + quad * 8;
    char* wbase = smem + w * 20480;         // wave-private region

    // prologue: stage chunk 0 -> buffer 0
    #pragma unroll
    for (int ks = 0; ks < 2; ks++)
        #pragma unroll
        for (int h = 0; h < 2; h++)
            ld_lds16(xgb + ks * 32 + h * 4,
                     wbase + (ks * 2 + h) * 1024 + lane * 16);
    #pragma unroll
    for (int ct = 0; ct < 3; ct++)
        #pragma unroll
        for (int ks = 0; ks < 2; ks++)
            ld_lds16(wgb + ct * 16 * C_ + ks * 32,
                     wbase + 4096 + (ct * 2 + ks) * 1024 + lane * 16);

    f32x4 acc[3];
    #pragma unroll
    for (int ct = 0; ct < 3; ct++)
        #pragma unroll
        for (int j = 0; j < 4; j++) acc[ct][j] = 0.0f;

    #pragma unroll
    for (int i = 0; i < 16; i++) {
        const int b = i & 1;
        char* cur = wbase + b * 10240;

        // wave-local drain: exactly this chunk's 10 stages are outstanding
        asm volatile("s_waitcnt vmcnt(0)" ::: "memory");
        __builtin_amdgcn_sched_barrier(0);

        // stage chunk i+1 into the other buffer (async; overlaps compute)
        if (i < 15) {
            const int k1 = (i + 1) * 64;
            char* nxt = wbase + (b ^ 1) * 10240;
            #pragma unroll
            for (int ks = 0; ks < 2; ks++)
                #pragma unroll
                for (int h = 0; h < 2; h++)
                    ld_lds16(xgb + k1 + ks * 32 + h * 4,
                             nxt + (ks * 2 + h) * 1024 + lane * 16);
            #pragma unroll
            for (int ct = 0; ct < 3; ct++)
                #pragma unroll
                for (int ks = 0; ks < 2; ks++)
                    ld_lds16(wgb + ct * 16 * C_ + k1 + ks * 32,
                             nxt + 4096 + (ct * 2 + ks) * 1024 + lane * 16);
        }

        // frag reads: each lane reads back exactly what it staged
        float4 xr[2][2];
        #pragma unroll
        for (int ks = 0; ks < 2; ks++)
            #pragma unroll
            for (int h = 0; h < 2; h++)
                xr[ks][h] = *reinterpret_cast<const float4*>(
                    cur + (ks * 2 + h) * 1024 + lane * 16);
        s16x8 wf[3][2];
        #pragma unroll
        for (int ct = 0; ct < 3; ct++)
            #pragma unroll
            for (int ks = 0; ks < 2; ks++)
                wf[ct][ks] = *reinterpret_cast<const s16x8*>(
                    cur + 4096 + (ct * 2 + ks) * 1024 + lane * 16);

        // pack fp32 -> bf16 A-frags and MFMA
        s16x8 af[2];
        #pragma unroll
        for (int ks = 0; ks < 2; ks++) {
            const float4 a = xr[ks][0], bv = xr[ks][1];
            uint4 pk;
            pk.x = pkbf(a.x, a.y);  pk.y = pkbf(a.z, a.w);
            pk.z = pkbf(bv.x, bv.y); pk.w = pkbf(bv.z, bv.w);
            af[ks] = *reinterpret_cast<s16x8*>(&pk);
        }
        #pragma unroll
        for (int ks = 0; ks < 2; ks++)
            #pragma unroll
            for (int ct = 0; ct < 3; ct++)
                acc[ct] = __builtin_amdgcn_mfma_f32_16x16x32_bf16(
                    af[ks], wf[ct][ks], acc[ct], 0, 0, 0);
    }

    // epilogue: C row = quad*4+reg, col = l15
    #pragma unroll
    for (int ct = 0; ct < 3; ct++) {
        int cbv = colb + ct * 16;
        int sel = cbv >> 6;                 // 0=K 1=Q 2=V, wave-uniform
        int h = (cbv & 63) + l15;
        int row0 = m0 + quad * 4;
        if (sel < 2) {
            unsigned short* dst = sel ? qb : kb;
            #pragma unroll
            for (int r = 0; r < 4; r++)
                dst[(size_t)(row0 + r) * H_ + h] = (unsigned short)rhu16(acc[ct][r]);
        } else {
            int tt = row0 - bb * T_;        // V transposed: 4 consecutive t
            uint2 pk;
            pk.x = pkbf(acc[ct][0], acc[ct][1]);
            pk.y = pkbf(acc[ct][2], acc[ct][3]);
            *reinterpret_cast<uint2*>(&vtb[((size_t)bb * H_ + h) * T_ + tt]) = pk;
        }
    }
}

// ---------------------------------------------------------------------------
// K2: attention. 512 blocks = (batch &7, 32-row q-tile), 4 waves; wave owns a
// 512-s quarter in 8 chunks of 64 s. Per iteration: 16 direct register loads
// (K waits leave V in flight through S-MFMA/exp), 32 MFMA. LDS: P round-trip
// (wave-private, stride 72) + 4-way split-KV combine epilogue.
// ---------------------------------------------------------------------------
__global__ __launch_bounds__(256, 2) void attn(
        const unsigned short* __restrict__ qb,
        const unsigned short* __restrict__ kb,
        const unsigned short* __restrict__ vtb,
        float* __restrict__ out) {
    __shared__ __align__(16) char smem[25728];
    // main loop: Pw per wave at smem + w*4608 (32 rows x 72 shorts)
    // epilogue (after syncthreads): Osf[3][32][66] f32 (25344B) + Ls[96] f32

    const int t = threadIdx.x, lane = t & 63, w = t >> 6;
    const int l15 = lane & 15, quad = lane >> 4;
    const int bb = blockIdx.x & 7;
    const int q0 = (blockIdx.x >> 3) << 5;
    const size_t kbase = (size_t)bb * T_ * H_;
    unsigned short* Pw = (unsigned short*)(smem + w * 4608);

    // Q B-frags (pre-scaled by 1/32 via Wq), kept in regs for all iterations
    s16x8 qf[2][2];
    #pragma unroll
    for (int rt = 0; rt < 2; rt++)
        #pragma unroll
        for (int ks = 0; ks < 2; ks++)
            qf[rt][ks] = *reinterpret_cast<const s16x8*>(
                &qb[kbase + (size_t)(q0 + rt * 16 + l15) * H_ + ks * 32 + quad * 8]);

    const int sw = w << 9;                 // this wave's s-quarter base
    const unsigned short* kq = kb + kbase + (size_t)(sw + l15) * H_ + quad * 8;
    const unsigned short* vq[4];
    #pragma unroll
    for (int ht = 0; ht < 4; ht++)
        vq[ht] = vtb + ((size_t)bb * H_ + ht * 16 + l15) * T_ + sw + quad * 8;

    f32x4 oacc[2][4];
    #pragma unroll
    for (int rt = 0; rt < 2; rt++)
        #pragma unroll
        for (int ht = 0; ht < 4; ht++)
            #pragma unroll
            for (int j = 0; j < 4; j++) oacc[rt][ht][j] = 0.0f;
    float l_run[2] = {0.0f, 0.0f};
    const f32x4 z4 = {0.0f, 0.0f, 0.0f, 0.0f};

    for (int it = 0; it < 8; it++) {
        // 16 loads issued back-to-back: 8 K-frags then 8 V-frags. Compiler
        // waits per-use: S-MFMA waits only K; V stays in flight until O-MFMA.
        s16x8 kf[4][2], vf[2][4];
        #pragma unroll
        for (int st = 0; st < 4; st++)
            #pragma unroll
            for (int ks = 0; ks < 2; ks++)
                kf[st][ks] = *reinterpret_cast<const s16x8*>(
                    kq + (size_t)(it * 64 + st * 16) * H_ + ks * 32);
        #pragma unroll
        for (int ks2 = 0; ks2 < 2; ks2++)
            #pragma unroll
            for (int ht = 0; ht < 4; ht++)
                vf[ks2][ht] = *reinterpret_cast<const s16x8*>(
                    vq[ht] + it * 64 + ks2 * 32);

        // S^T = K.Q^T : C row = s (quad*4+r), col = q (l15)
        f32x4 sacc[2][4];
        #pragma unroll
        for (int rt = 0; rt < 2; rt++)
            #pragma unroll
            for (int st = 0; st < 4; st++) {
                f32x4 s0v = __builtin_amdgcn_mfma_f32_16x16x32_bf16(
                    kf[st][0], qf[rt][0], z4, 0, 0, 0);
                sacc[rt][st] = __builtin_amdgcn_mfma_f32_16x16x32_bf16(
                    kf[st][1], qf[rt][1], s0v, 0, 0, 0);
            }

        // exp (scores bounded; no max-sub) + packed P write (stride 72)
        #pragma unroll
        for (int rt = 0; rt < 2; rt++) {
            float ls = 0.0f;
            #pragma unroll
            for (int st = 0; st < 4; st++) {
                float p0 = __expf(sacc[rt][st][0]);
                float p1 = __expf(sacc[rt][st][1]);
                float p2 = __expf(sacc[rt][st][2]);
                float p3 = __expf(sacc[rt][st][3]);
                ls += (p0 + p1) + (p2 + p3);
                uint2 pk; pk.x = pkbf(p0, p1); pk.y = pkbf(p2, p3);
                *reinterpret_cast<uint2*>(
                    &Pw[(rt * 16 + l15) * 72 + st * 16 + quad * 4]) = pk;
            }
            l_run[rt] += ls;
        }

        // O += P.V : two 32-s k-steps; P read same-wave LDS (lgkmcnt only)
        #pragma unroll
        for (int rt = 0; rt < 2; rt++)
            #pragma unroll
            for (int ks2 = 0; ks2 < 2; ks2++) {
                s16x8 pf = *reinterpret_cast<const s16x8*>(
                    &Pw[(rt * 16 + l15) * 72 + ks2 * 32 + quad * 8]);
                #pragma unroll
                for (int ht = 0; ht < 4; ht++)
                    oacc[rt][ht] = __builtin_amdgcn_mfma_f32_16x16x32_bf16(
                        pf, vf[ks2][ht], oacc[rt][ht], 0, 0, 0);
            }
    }

    // l: each lane's partial covers its s-quarter rows for q=l15
    #pragma unroll
    for (int rt = 0; rt < 2; rt++) {
        l_run[rt] += __shfl_xor(l_run[rt], 16);
        l_run[rt] += __shfl_xor(l_run[rt], 32);
    }

    // 4-way split-KV combine (plain sums — no max terms)
    __syncthreads();
    float* Osf = (float*)smem;             // [3][32][66]
    float* Ls  = (float*)smem + 3 * 32 * 66;
    if (w > 0) {
        int wi = w - 1;
        #pragma unroll
        for (int rt = 0; rt < 2; rt++) {
            if (quad == 0) Ls[wi * 32 + rt * 16 + l15] = l_run[rt];
            #pragma unroll
            for (int ht = 0; ht < 4; ht++)
                #pragma unroll
                for (int r = 0; r < 4; r++)
                    Osf[wi * 2112 + (rt * 16 + quad * 4 + r) * 66 + ht * 16 + l15] = oacc[rt][ht][r];
        }
    }
    __syncthreads();
    if (w == 0) {
        #pragma unroll
        for (int rt = 0; rt < 2; rt++)
            #pragma unroll
            for (int r = 0; r < 4; r++) {
                int row = rt * 16 + quad * 4 + r;
                float lt = __shfl(l_run[rt], quad * 4 + r)
                         + Ls[0 * 32 + row] + Ls[1 * 32 + row] + Ls[2 * 32 + row];
                float inv = 1.0f / lt;
                #pragma unroll
                for (int ht = 0; ht < 4; ht++) {
                    float o = oacc[rt][ht][r]
                            + Osf[0 * 2112 + row * 66 + ht * 16 + l15]
                            + Osf[1 * 2112 + row * 66 + ht * 16 + l15]
                            + Osf[2 * 2112 + row * 66 + ht * 16 + l15];
                    out[kbase + (size_t)(q0 + row) * H_ + ht * 16 + l15] = o * inv;
                }
            }
    }
}

extern "C" void kernel_launch(void* const* d_in, const int* in_sizes, int n_in,
                              void* d_out, int out_size, void* d_ws, size_t ws_size,
                              hipStream_t stream) {
    const float* x  = (const float*)d_in[0];
    const float* Wk = (const float*)d_in[1];
    const float* Wq = (const float*)d_in[2];
    const float* Wv = (const float*)d_in[3];

    unsigned short* kb  = (unsigned short*)d_ws;               // 2 MB
    unsigned short* qbf = kb  + (size_t)B_ * T_ * H_;          // 2 MB
    unsigned short* vtb = qbf + (size_t)B_ * T_ * H_;          // 2 MB
    unsigned short* Wt  = (unsigned short*)d_out;              // 384 KB scratch

    wconv<<<48,   256, 0, stream>>>(Wk, Wq, Wv, Wt);
    qkv  <<<1024, 256, 0, stream>>>(x, Wt, kb, qbf, vtb);
    attn <<<512,  256, 0, stream>>>(qbf, kb, vtb, (float*)d_out);
}

// Round 6
// 151.997 us; speedup vs baseline: 1.2674x; 1.2674x over previous
//
#include <hip/hip_runtime.h>
#include <stdint.h>

// Head: x[8,2048,1024] fp32; Wk/Wq/Wv [1024,64] fp32 -> out [8,2048,64] fp32
// R13 (resubmit — R5 bench was an acquisition timeout, no data).
// qkv = R4's exact proven structure (block-coop global_load_lds dbuf,
// 1 syncthreads/chunk, identical LDS layouts + frag formulas) with ONE
// change: 8 waves/block (512 thr) instead of 4, same 32x192 tile, same 64KB
// LDS, same 512 blocks. Waves/SIMD 2->4: when one block drains vmcnt(0) at
// the barrier, the co-resident block now has 8 waves to keep SIMDs fed.
// R10/R11/R12 (direct-load / reg-dbuf / wave-private-LDS) all LOST to R4
// (76/57/80 vs 40.8): kernel is latency/TLP-bound; every redesign cut
// waves/SIMD or loads-in-flight. waves_per_eu(4,4) pins regalloc at real
// occupancy (no R10-style 32-VGPR squeeze). wconv + attn unchanged (R9).

#define B_ 8
#define T_ 2048
#define C_ 1024
#define H_ 64

typedef float f32x4 __attribute__((ext_vector_type(4)));
typedef short s16x8 __attribute__((ext_vector_type(8)));

__device__ __forceinline__ unsigned int rhu16(float f) {
    return (__float_as_uint(f) + 0x8000u) >> 16;
}
__device__ __forceinline__ unsigned int pkbf(float lo, float hi) {
    unsigned int a = __float_as_uint(lo) + 0x8000u;
    unsigned int b = __float_as_uint(hi) + 0x8000u;
    return __builtin_amdgcn_perm(b, a, 0x07060302u);   // bytes [b3 b2 a3 a2]
}
// async global->LDS, 16B per lane; LDS dest = wave-uniform base + lane*16
__device__ __forceinline__ void ld_lds16(const void* g, void* l) {
    __builtin_amdgcn_global_load_lds(
        (const __attribute__((address_space(1))) unsigned int*)g,
        (__attribute__((address_space(3))) unsigned int*)l, 16, 0, 0);
}

// ---------------------------------------------------------------------------
// K0: 48 blocks = 3 mats x 16 c-groups of 64. Coalesced read, LDS transpose
// (stride 65), coalesced bf16 write. Wq pre-scaled by 1/32 (C^-0.5).
// ---------------------------------------------------------------------------
__global__ __launch_bounds__(256) void wconv(const float* __restrict__ Wk,
        const float* __restrict__ Wq, const float* __restrict__ Wv,
        unsigned short* __restrict__ Wt) {
    __shared__ float ls[64 * 65];
    const int bx = blockIdx.x, t = threadIdx.x;
    const int mat = bx >> 4, c0 = (bx & 15) << 6;
    const float* W = (mat == 0) ? Wk : ((mat == 1) ? Wq : Wv);
    const float sc = (mat == 1) ? 0.03125f : 1.0f;
    #pragma unroll
    for (int k = 0; k < 4; k++) {
        int i = t + (k << 8);
        int cr = i >> 4, hq = (i & 15) << 2;
        float4 v = *reinterpret_cast<const float4*>(&W[(size_t)(c0 + cr) * H_ + hq]);
        ls[cr * 65 + hq + 0] = v.x; ls[cr * 65 + hq + 1] = v.y;
        ls[cr * 65 + hq + 2] = v.z; ls[cr * 65 + hq + 3] = v.w;
    }
    __syncthreads();
    #pragma unroll
    for (int k = 0; k < 4; k++) {
        int i = t + (k << 8);
        int h = i >> 4, cq = (i & 15) << 2;
        float a = ls[(cq + 0) * 65 + h] * sc, b = ls[(cq + 1) * 65 + h] * sc;
        float c = ls[(cq + 2) * 65 + h] * sc, d = ls[(cq + 3) * 65 + h] * sc;
        uint2 o; o.x = pkbf(a, b); o.y = pkbf(c, d);
        *reinterpret_cast<uint2*>(&Wt[(size_t)(mat * 64 + h) * C_ + c0 + cq]) = o;
    }
}

// ---------------------------------------------------------------------------
// K1: QKV projection — R4 structure at 8 waves/block. 512 blocks x 512 thr;
// block = 32 rows x 192 cols; wave (wr=w>>2, wc=w&3) owns 16 rows x 48 cols.
// Per 64-k chunk per wave: 1 x-stage + 3 W-stages (global_load_lds 16B),
// ds_read frags, pack, 6 MFMA, 1 barrier. LDS dbuf 64KB -> 2 blocks/CU,
// 16 waves/CU = 4 waves/SIMD.
// ---------------------------------------------------------------------------
__global__ __launch_bounds__(512) __attribute__((amdgpu_waves_per_eu(4, 4)))
void qkv(const float* __restrict__ x,
        const unsigned short* __restrict__ Wt,
        unsigned short* __restrict__ kb, unsigned short* __restrict__ qb,
        unsigned short* __restrict__ vtb) {
    __shared__ __align__(16) char smem[65536];   // xbuf 2x8192 | wbuf 2x24576
    char* xb = smem;
    char* wb = smem + 16384;

    const int t = threadIdx.x, lane = t & 63, w = t >> 6;   // w in 0..7
    const int l15 = lane & 15, quad = lane >> 4;
    const int bx = blockIdx.x;
    const int bb = bx >> 6;                 // batch
    const int mt = bx & 63;                 // 32-row tile within batch
    const int m0 = bb * T_ + mt * 32;
    const int wr = w >> 2;                  // row-half of the 32-row tile
    const int colb = (w & 3) * 48;          // 48-col strip

    // per-wave async shares: 1 x-instr (id = w), 3 W-instrs (g = w*3+n).
    // x LDS layout [rg][j][quad][l15] @ id*1024+lane*16 (id = rg*4+j);
    // W LDS layout [g][k8][col&7]    @ g*1024+lane*16.
    size_t xg; int xl;
    {
        int rg = w >> 2, j = w & 3;
        xg = (size_t)(m0 + rg * 16 + l15) * C_ + j * 16 + quad * 4;
        xl = w * 1024 + lane * 16;
    }
    size_t wg[3]; int wl[3];
    #pragma unroll
    for (int n = 0; n < 3; n++) {
        int g = w * 3 + n;
        wg[n] = (size_t)(g * 8 + (lane & 7)) * C_ + (lane >> 3) * 8;
        wl[n] = g * 1024 + lane * 16;
    }

    // prologue: stage chunk 0
    ld_lds16(x + xg, xb + xl);
    #pragma unroll
    for (int n = 0; n < 3; n++) ld_lds16(Wt + wg[n], wb + wl[n]);
    __syncthreads();

    f32x4 acc[3];
    #pragma unroll
    for (int ct = 0; ct < 3; ct++)
        #pragma unroll
        for (int j = 0; j < 4; j++) acc[ct][j] = 0.0f;

    #pragma unroll
    for (int i = 0; i < 16; i++) {
        const int cb = i & 1;
        const float* xc = (const float*)(xb + cb * 8192);
        const unsigned short* wcp = (const unsigned short*)(wb + cb * 24576);

        // frag reads from LDS (no outstanding vmcnt here: drained at barrier)
        float4 xr[2][2];
        #pragma unroll
        for (int ks = 0; ks < 2; ks++)
            #pragma unroll
            for (int h = 0; h < 2; h++) {
                int c = ks * 32 + quad * 8 + h * 4;
                int j = c >> 4, u = (c & 15) >> 2;
                xr[ks][h] = *reinterpret_cast<const float4*>(
                    xc + (wr * 4 + j) * 256 + u * 64 + l15 * 4);
            }
        s16x8 wfr[3][2];
        #pragma unroll
        for (int ct = 0; ct < 3; ct++)
            #pragma unroll
            for (int ks = 0; ks < 2; ks++) {
                int col = colb + ct * 16 + l15;
                wfr[ct][ks] = *reinterpret_cast<const s16x8*>(
                    wcp + (col >> 3) * 512 + ((4 * ks + quad) * 8 + (col & 7)) * 8);
            }

        // prefetch chunk i+1 into the other buffer (async, overlaps compute)
        if (i < 15) {
            const int c1 = (i + 1) * 64;
            char* xn = xb + (cb ^ 1) * 8192;
            char* wn = wb + (cb ^ 1) * 24576;
            ld_lds16(x + xg + c1, xn + xl);
            #pragma unroll
            for (int n = 0; n < 3; n++) ld_lds16(Wt + wg[n] + c1, wn + wl[n]);
        }

        // pack fp32 -> bf16 A-frags and MFMA
        s16x8 af[2];
        #pragma unroll
        for (int ks = 0; ks < 2; ks++) {
            const float4 a = xr[ks][0], b = xr[ks][1];
            uint4 pk;
            pk.x = pkbf(a.x, a.y); pk.y = pkbf(a.z, a.w);
            pk.z = pkbf(b.x, b.y); pk.w = pkbf(b.z, b.w);
            af[ks] = *reinterpret_cast<s16x8*>(&pk);
        }
        #pragma unroll
        for (int ks = 0; ks < 2; ks++)
            #pragma unroll
            for (int ct = 0; ct < 3; ct++)
                acc[ct] = __builtin_amdgcn_mfma_f32_16x16x32_bf16(
                    af[ks], wfr[ct][ks], acc[ct], 0, 0, 0);
        __syncthreads();   // waves' asyncs drained (compiler vmcnt(0)) + swap
    }

    // epilogue: C row = quad*4+reg (within wave's 16-row strip), col = l15
    #pragma unroll
    for (int ct = 0; ct < 3; ct++) {
        int cbv = colb + ct * 16;
        int sel = cbv >> 6;                 // 0=K 1=Q 2=V, wave-uniform
        int h = (cbv & 63) + l15;
        int row0 = m0 + wr * 16 + quad * 4;
        if (sel < 2) {
            unsigned short* dst = sel ? qb : kb;
            #pragma unroll
            for (int r = 0; r < 4; r++)
                dst[(size_t)(row0 + r) * H_ + h] = (unsigned short)rhu16(acc[ct][r]);
        } else {
            int tt = row0 - bb * T_;        // V transposed: 4 consecutive t
            uint2 pk;
            pk.x = pkbf(acc[ct][0], acc[ct][1]);
            pk.y = pkbf(acc[ct][2], acc[ct][3]);
            *reinterpret_cast<uint2*>(&vtb[((size_t)bb * H_ + h) * T_ + tt]) = pk;
        }
    }
}

// ---------------------------------------------------------------------------
// K2: attention. 512 blocks = (batch &7, 32-row q-tile), 4 waves; wave owns a
// 512-s quarter in 8 chunks of 64 s. Per iteration: 16 direct register loads
// (K waits leave V in flight through S-MFMA/exp), 32 MFMA. LDS: P round-trip
// (wave-private, stride 72) + 4-way split-KV combine epilogue.
// ---------------------------------------------------------------------------
__global__ __launch_bounds__(256, 2) void attn(
        const unsigned short* __restrict__ qb,
        const unsigned short* __restrict__ kb,
        const unsigned short* __restrict__ vtb,
        float* __restrict__ out) {
    __shared__ __align__(16) char smem[25728];
    // main loop: Pw per wave at smem + w*4608 (32 rows x 72 shorts)
    // epilogue (after syncthreads): Osf[3][32][66] f32 (25344B) + Ls[96] f32

    const int t = threadIdx.x, lane = t & 63, w = t >> 6;
    const int l15 = lane & 15, quad = lane >> 4;
    const int bb = blockIdx.x & 7;
    const int q0 = (blockIdx.x >> 3) << 5;
    const size_t kbase = (size_t)bb * T_ * H_;
    unsigned short* Pw = (unsigned short*)(smem + w * 4608);

    // Q B-frags (pre-scaled by 1/32 via Wq), kept in regs for all iterations
    s16x8 qf[2][2];
    #pragma unroll
    for (int rt = 0; rt < 2; rt++)
        #pragma unroll
        for (int ks = 0; ks < 2; ks++)
            qf[rt][ks] = *reinterpret_cast<const s16x8*>(
                &qb[kbase + (size_t)(q0 + rt * 16 + l15) * H_ + ks * 32 + quad * 8]);

    const int sw = w << 9;                 // this wave's s-quarter base
    const unsigned short* kq = kb + kbase + (size_t)(sw + l15) * H_ + quad * 8;
    const unsigned short* vq[4];
    #pragma unroll
    for (int ht = 0; ht < 4; ht++)
        vq[ht] = vtb + ((size_t)bb * H_ + ht * 16 + l15) * T_ + sw + quad * 8;

    f32x4 oacc[2][4];
    #pragma unroll
    for (int rt = 0; rt < 2; rt++)
        #pragma unroll
        for (int ht = 0; ht < 4; ht++)
            #pragma unroll
            for (int j = 0; j < 4; j++) oacc[rt][ht][j] = 0.0f;
    float l_run[2] = {0.0f, 0.0f};
    const f32x4 z4 = {0.0f, 0.0f, 0.0f, 0.0f};

    for (int it = 0; it < 8; it++) {
        // 16 loads issued back-to-back: 8 K-frags then 8 V-frags. Compiler
        // waits per-use: S-MFMA waits only K; V stays in flight until O-MFMA.
        s16x8 kf[4][2], vf[2][4];
        #pragma unroll
        for (int st = 0; st < 4; st++)
            #pragma unroll
            for (int ks = 0; ks < 2; ks++)
                kf[st][ks] = *reinterpret_cast<const s16x8*>(
                    kq + (size_t)(it * 64 + st * 16) * H_ + ks * 32);
        #pragma unroll
        for (int ks2 = 0; ks2 < 2; ks2++)
            #pragma unroll
            for (int ht = 0; ht < 4; ht++)
                vf[ks2][ht] = *reinterpret_cast<const s16x8*>(
                    vq[ht] + it * 64 + ks2 * 32);

        // S^T = K.Q^T : C row = s (quad*4+r), col = q (l15)
        f32x4 sacc[2][4];
        #pragma unroll
        for (int rt = 0; rt < 2; rt++)
            #pragma unroll
            for (int st = 0; st < 4; st++) {
                f32x4 s0v = __builtin_amdgcn_mfma_f32_16x16x32_bf16(
                    kf[st][0], qf[rt][0], z4, 0, 0, 0);
                sacc[rt][st] = __builtin_amdgcn_mfma_f32_16x16x32_bf16(
                    kf[st][1], qf[rt][1], s0v, 0, 0, 0);
            }

        // exp (scores bounded; no max-sub) + packed P write (stride 72)
        #pragma unroll
        for (int rt = 0; rt < 2; rt++) {
            float ls = 0.0f;
            #pragma unroll
            for (int st = 0; st < 4; st++) {
                float p0 = __expf(sacc[rt][st][0]);
                float p1 = __expf(sacc[rt][st][1]);
                float p2 = __expf(sacc[rt][st][2]);
                float p3 = __expf(sacc[rt][st][3]);
                ls += (p0 + p1) + (p2 + p3);
                uint2 pk; pk.x = pkbf(p0, p1); pk.y = pkbf(p2, p3);
                *reinterpret_cast<uint2*>(
                    &Pw[(rt * 16 + l15) * 72 + st * 16 + quad * 4]) = pk;
            }
            l_run[rt] += ls;
        }

        // O += P.V : two 32-s k-steps; P read same-wave LDS (lgkmcnt only)
        #pragma unroll
        for (int rt = 0; rt < 2; rt++)
            #pragma unroll
            for (int ks2 = 0; ks2 < 2; ks2++) {
                s16x8 pf = *reinterpret_cast<const s16x8*>(
                    &Pw[(rt * 16 + l15) * 72 + ks2 * 32 + quad * 8]);
                #pragma unroll
                for (int ht = 0; ht < 4; ht++)
                    oacc[rt][ht] = __builtin_amdgcn_mfma_f32_16x16x32_bf16(
                        pf, vf[ks2][ht], oacc[rt][ht], 0, 0, 0);
            }
    }

    // l: each lane's partial covers its s-quarter rows for q=l15
    #pragma unroll
    for (int rt = 0; rt < 2; rt++) {
        l_run[rt] += __shfl_xor(l_run[rt], 16);
        l_run[rt] += __shfl_xor(l_run[rt], 32);
    }

    // 4-way split-KV combine (plain sums — no max terms)
    __syncthreads();
    float* Osf = (float*)smem;             // [3][32][66]
    float* Ls  = (float*)smem + 3 * 32 * 66;
    if (w > 0) {
        int wi = w - 1;
        #pragma unroll
        for (int rt = 0; rt < 2; rt++) {
            if (quad == 0) Ls[wi * 32 + rt * 16 + l15] = l_run[rt];
            #pragma unroll
            for (int ht = 0; ht < 4; ht++)
                #pragma unroll
                for (int r = 0; r < 4; r++)
                    Osf[wi * 2112 + (rt * 16 + quad * 4 + r) * 66 + ht * 16 + l15] = oacc[rt][ht][r];
        }
    }
    __syncthreads();
    if (w == 0) {
        #pragma unroll
        for (int rt = 0; rt < 2; rt++)
            #pragma unroll
            for (int r = 0; r < 4; r++) {
                int row = rt * 16 + quad * 4 + r;
                float lt = __shfl(l_run[rt], quad * 4 + r)
                         + Ls[0 * 32 + row] + Ls[1 * 32 + row] + Ls[2 * 32 + row];
                float inv = 1.0f / lt;
                #pragma unroll
                for (int ht = 0; ht < 4; ht++) {
                    float o = oacc[rt][ht][r]
                            + Osf[0 * 2112 + row * 66 + ht * 16 + l15]
                            + Osf[1 * 2112 + row * 66 + ht * 16 + l15]
                            + Osf[2 * 2112 + row * 66 + ht * 16 + l15];
                    out[kbase + (size_t)(q0 + row) * H_ + ht * 16 + l15] = o * inv;
                }
            }
    }
}

extern "C" void kernel_launch(void* const* d_in, const int* in_sizes, int n_in,
                              void* d_out, int out_size, void* d_ws, size_t ws_size,
                              hipStream_t stream) {
    const float* x  = (const float*)d_in[0];
    const float* Wk = (const float*)d_in[1];
    const float* Wq = (const float*)d_in[2];
    const float* Wv = (const float*)d_in[3];

    unsigned short* kb  = (unsigned short*)d_ws;               // 2 MB
    unsigned short* qbf = kb  + (size_t)B_ * T_ * H_;          // 2 MB
    unsigned short* vtb = qbf + (size_t)B_ * T_ * H_;          // 2 MB
    unsigned short* Wt  = (unsigned short*)d_out;              // 384 KB scratch

    wconv<<<48,  256, 0, stream>>>(Wk, Wq, Wv, Wt);
    qkv  <<<512, 512, 0, stream>>>(x, Wt, kb, qbf, vtb);
    attn <<<512, 256, 0, stream>>>(qbf, kb, vtb, (float*)d_out);
}